// Round 1
// baseline (991.662 us; speedup 1.0000x reference)
//
#include <hip/hip_runtime.h>
#include <hip/hip_bf16.h>
#include <math.h>

#define B_DIM 512
#define E_DIM 512
#define W_DIM 64
#define V_DIM 32000
#define H_DIM 5120

typedef short bf16x8 __attribute__((ext_vector_type(8)));
typedef float f32x4 __attribute__((ext_vector_type(4)));

static __device__ __forceinline__ unsigned short f2bf(float x) {
  union { float f; unsigned u; } c; c.f = x;
  unsigned r = c.u + 0x7FFFu + ((c.u >> 16) & 1u);
  return (unsigned short)(r >> 16);
}
static __device__ __forceinline__ unsigned pack2(float a, float b) {
  return (unsigned)f2bf(a) | ((unsigned)f2bf(b) << 16);
}

// ---------------- Attention: one block per batch row ----------------
__global__ __launch_bounds__(256) void attn_kernel(
    const float* __restrict__ state, const float* __restrict__ encode,
    const float* __restrict__ aW1, const float* __restrict__ aW2,
    const float* __restrict__ aW3, float* __restrict__ ctx) {
  const int b = blockIdx.x;
  const int tid = threadIdx.x;
  __shared__ float rq[512];
  __shared__ float sc[64];
  rq[tid]       = state[(size_t)b * 512 + tid]       * aW1[tid];
  rq[tid + 256] = state[(size_t)b * 512 + tid + 256] * aW1[tid + 256];
  __syncthreads();
  const int lane = tid & 63, wv = tid >> 6;
  const float* enc = encode + (size_t)b * 64 * 512;
  for (int w = wv; w < 64; w += 4) {
    const float* er  = enc + w * 512;
    const float* w2r = aW2 + w * 512;
    const float* w3r = aW3 + w * 512;
    float s = 0.f;
#pragma unroll
    for (int k = 0; k < 8; ++k) {
      int e = lane + k * 64;
      s += tanhf(rq[e] * er[e] * w2r[e]) * w3r[e];
    }
#pragma unroll
    for (int o = 32; o; o >>= 1) s += __shfl_xor(s, o, 64);
    if (lane == 0) sc[w] = s;
  }
  __syncthreads();
  if (tid < 64) {
    float v = sc[tid];
    float mx = v;
#pragma unroll
    for (int o = 32; o; o >>= 1) mx = fmaxf(mx, __shfl_xor(mx, o, 64));
    float e = __expf(v - mx);
    float sm = e;
#pragma unroll
    for (int o = 32; o; o >>= 1) sm += __shfl_xor(sm, o, 64);
    sc[tid] = e / sm;
  }
  __syncthreads();
  for (int e = tid; e < 512; e += 256) {
    float acc = 0.f;
#pragma unroll 8
    for (int w = 0; w < 64; ++w) acc += sc[w] * enc[w * 512 + e];
    ctx[(size_t)b * 512 + e] = acc;
  }
}

// ---------------- pack three [512,512] sources ----------------
// mode 0: dst[(s*512 + b)*512 + e]  (stack for GRU pre-projection)
// mode 1: dst[b*1536 + s*512 + e]   (concat for dense input)
__global__ __launch_bounds__(256) void pack3(
    const float* __restrict__ s0, const float* __restrict__ s1,
    const float* __restrict__ s2, float* __restrict__ dst, int mode) {
  const int s = blockIdx.y;
  const int i = blockIdx.x * 256 + threadIdx.x;
  const float* src = (s == 0) ? s0 : ((s == 1) ? s1 : s2);
  const float v = src[i];
  if (mode == 0) {
    dst[(size_t)s * 262144 + i] = v;
  } else {
    const int b = i >> 9, e = i & 511;
    dst[(size_t)b * 1536 + s * 512 + e] = v;
  }
}

// ---------------- GRU gate math ----------------
// X: [B,1536] row b (already + bi).  R: rows stride rstride (0 => broadcast br row, already + br).
__global__ __launch_bounds__(256) void gru_gate(
    const float* __restrict__ X, const float* __restrict__ R, int rstride,
    const float* __restrict__ hprev, float* __restrict__ hout) {
  const int i = blockIdx.x * 256 + threadIdx.x;  // 0..262143
  const int b = i >> 9, e = i & 511;
  const float* Xr = X + (size_t)b * 1536;
  const float* Rr = R + (size_t)b * rstride;
  const float xz = Xr[e], xr = Xr[512 + e], xh = Xr[1024 + e];
  const float rz = Rr[e], rr = Rr[512 + e], rh = Rr[1024 + e];
  const float h = hprev ? hprev[i] : 0.f;
  const float z = 1.f / (1.f + __expf(-(xz + rz)));
  const float r = 1.f / (1.f + __expf(-(xr + rr)));
  const float hh = tanhf(xh + r * rh);
  hout[i] = z * h + (1.f - z) * hh;
}

// ---------------- bf16 MFMA GEMM: C = act(A@B + bias) ----------------
// A: [M,K] f32 row-major, B: [K,N] f32 row-major, C: [M,N] f32.
// M%128==0, N%128==0, K%32==0.  ACT: 0=none, 1=tanh.
#define LSTR 40  // 32 + 8 bf16 pad: rows stay 16B-aligned, frag reads bank-balanced

template <int ACT>
__global__ __launch_bounds__(256, 2) void gemm_k(
    const float* __restrict__ A, const float* __restrict__ B,
    const float* __restrict__ bias, float* __restrict__ C,
    int M, int N, int K) {
  __shared__ unsigned short As[128 * LSTR];
  __shared__ unsigned short Bs[128 * LSTR];
  const int tid = threadIdx.x;
  const int tiles_m = M >> 7;
  const int mt = blockIdx.x % tiles_m;
  const int nt = blockIdx.x / tiles_m;
  const long m0 = (long)mt * 128, n0 = (long)nt * 128;
  const int a_kq = (tid & 7) << 2;   // k offset 0..28
  const int a_m  = tid >> 3;         // row 0..31 (+32r)
  const int b_nq = (tid & 31) << 2;  // n offset 0..124
  const int b_kg = (tid >> 5) << 2;  // k base 0..28
  const int lane = tid & 63;
  const int wid = tid >> 6;
  const int wm = (wid >> 1) << 6, wn = (wid & 1) << 6;
  const int lr = lane & 15, lg = lane >> 4;

  f32x4 acc[4][4];
#pragma unroll
  for (int i = 0; i < 4; ++i)
#pragma unroll
    for (int j = 0; j < 4; ++j) acc[i][j] = f32x4{0.f, 0.f, 0.f, 0.f};

  for (int kk = 0; kk < K; kk += 32) {
    // stage A tile [128 x 32] -> As (row-major, k contiguous)
#pragma unroll
    for (int r = 0; r < 4; ++r) {
      const int m = a_m + (r << 5);
      const float4 v = *(const float4*)(A + (m0 + m) * (long)K + kk + a_kq);
      uint2 p;
      p.x = pack2(v.x, v.y);
      p.y = pack2(v.z, v.w);
      *(uint2*)(As + m * LSTR + a_kq) = p;
    }
    // stage B tile [32 x 128] transposed -> Bs (n-major, k contiguous)
    {
      const float* bp = B + (long)(kk + b_kg) * N + n0 + b_nq;
      const float4 r0 = *(const float4*)(bp);
      const float4 r1 = *(const float4*)(bp + N);
      const float4 r2 = *(const float4*)(bp + 2 * (long)N);
      const float4 r3 = *(const float4*)(bp + 3 * (long)N);
      uint2 p;
      p.x = pack2(r0.x, r1.x); p.y = pack2(r2.x, r3.x);
      *(uint2*)(Bs + (b_nq + 0) * LSTR + b_kg) = p;
      p.x = pack2(r0.y, r1.y); p.y = pack2(r2.y, r3.y);
      *(uint2*)(Bs + (b_nq + 1) * LSTR + b_kg) = p;
      p.x = pack2(r0.z, r1.z); p.y = pack2(r2.z, r3.z);
      *(uint2*)(Bs + (b_nq + 2) * LSTR + b_kg) = p;
      p.x = pack2(r0.w, r1.w); p.y = pack2(r2.w, r3.w);
      *(uint2*)(Bs + (b_nq + 3) * LSTR + b_kg) = p;
    }
    __syncthreads();
    bf16x8 af[4], bfr[4];
#pragma unroll
    for (int i = 0; i < 4; ++i)
      af[i] = *(const bf16x8*)(As + (wm + i * 16 + lr) * LSTR + (lg << 3));
#pragma unroll
    for (int j = 0; j < 4; ++j)
      bfr[j] = *(const bf16x8*)(Bs + (wn + j * 16 + lr) * LSTR + (lg << 3));
#pragma unroll
    for (int i = 0; i < 4; ++i)
#pragma unroll
      for (int j = 0; j < 4; ++j)
        acc[i][j] = __builtin_amdgcn_mfma_f32_16x16x32_bf16(af[i], bfr[j], acc[i][j], 0, 0, 0);
    __syncthreads();
  }
  // epilogue: C row = (lane>>4)*4 + reg, col = lane&15 within each 16x16 frag
#pragma unroll
  for (int j = 0; j < 4; ++j) {
    const long col = n0 + wn + j * 16 + lr;
    const float bv = bias ? bias[col] : 0.f;
#pragma unroll
    for (int i = 0; i < 4; ++i) {
      const long row = m0 + wm + i * 16 + (lg << 2);
#pragma unroll
      for (int r = 0; r < 4; ++r) {
        float x = acc[i][j][r] + bv;
        if (ACT == 1) x = tanhf(x);
        C[(row + r) * N + col] = x;
      }
    }
  }
}

// ---------------- row softmax, in place, [512, 32000] ----------------
__global__ __launch_bounds__(256) void softmax_rows(float* __restrict__ x) {
  const int b = blockIdx.x;
  float* row = x + (size_t)b * V_DIM;
  const int tid = threadIdx.x;
  __shared__ float red[4];
  const float4* r4 = (const float4*)row;
  float mx = -3.4e38f;
  for (int i = tid; i < V_DIM / 4; i += 256) {
    float4 v = r4[i];
    mx = fmaxf(mx, fmaxf(fmaxf(v.x, v.y), fmaxf(v.z, v.w)));
  }
#pragma unroll
  for (int o = 32; o; o >>= 1) mx = fmaxf(mx, __shfl_xor(mx, o, 64));
  if ((tid & 63) == 0) red[tid >> 6] = mx;
  __syncthreads();
  mx = fmaxf(fmaxf(red[0], red[1]), fmaxf(red[2], red[3]));
  __syncthreads();
  float s = 0.f;
  for (int i = tid; i < V_DIM / 4; i += 256) {
    float4 v = r4[i];
    s += __expf(v.x - mx) + __expf(v.y - mx) + __expf(v.z - mx) + __expf(v.w - mx);
  }
#pragma unroll
  for (int o = 32; o; o >>= 1) s += __shfl_xor(s, o, 64);
  if ((tid & 63) == 0) red[tid >> 6] = s;
  __syncthreads();
  s = red[0] + red[1] + red[2] + red[3];
  const float inv = 1.f / s;
  float4* w4p = (float4*)row;
  for (int i = tid; i < V_DIM / 4; i += 256) {
    float4 v = r4[i];
    float4 o4;
    o4.x = __expf(v.x - mx) * inv;
    o4.y = __expf(v.y - mx) * inv;
    o4.z = __expf(v.z - mx) * inv;
    o4.w = __expf(v.w - mx) * inv;
    w4p[i] = o4;
  }
}

extern "C" void kernel_launch(void* const* d_in, const int* in_sizes, int n_in,
                              void* d_out, int out_size, void* d_ws, size_t ws_size,
                              hipStream_t stream) {
  const float* y      = (const float*)d_in[0];
  const float* state  = (const float*)d_in[1];
  const float* encode = (const float*)d_in[2];
  const float* aW1    = (const float*)d_in[3];
  const float* aW2    = (const float*)d_in[4];
  const float* aW3    = (const float*)d_in[5];
  const float* gk     = (const float*)d_in[6];
  const float* grk    = (const float*)d_in[7];
  const float* gb     = (const float*)d_in[8];
  const float* w1     = (const float*)d_in[9];
  const float* b1     = (const float*)d_in[10];
  const float* w2     = (const float*)d_in[11];
  const float* b2     = (const float*)d_in[12];
  const float* w3     = (const float*)d_in[13];
  const float* b3     = (const float*)d_in[14];
  float* out = (float*)d_out;
  float* ws = (float*)d_ws;

  float* ctx = ws;                 // 262144
  float* seq = ws + 262144;        // 786432  rows: t*512+b
  float* X   = ws + 1048576;       // 2359296 rows: t*512+b, cols 1536
  float* R   = ws + 3407872;       // 786432
  float* hg1 = ws + 4194304;       // 262144
  float* hg2 = ws + 4456448;       // 262144
  float* g   = ws + 4718592;       // 786432
  float* dd1 = ws + 5505024;       // 2621440
  float* dd2 = ws + 8126464;       // 2621440

  float* g_out = out;                               // [512, 32000]
  float* h3 = out + (size_t)B_DIM * V_DIM;          // new_state [512, 512]

  const float* bi = gb;
  const float* br = gb + 1536;

  attn_kernel<<<512, 256, 0, stream>>>(state, encode, aW1, aW2, aW3, ctx);
  pack3<<<dim3(1024, 3), 256, 0, stream>>>(state, ctx, y, seq, 0);
  // Xall = seq @ gk + bi : [1536,512]@[512,1536]
  gemm_k<0><<<12 * 12, 256, 0, stream>>>(seq, gk, bi, X, 1536, 1536, 512);
  // GRU t=0 (h=0 -> R row = br)
  gru_gate<<<1024, 256, 0, stream>>>(X, br, 0, nullptr, hg1);
  // GRU t=1
  gemm_k<0><<<4 * 12, 256, 0, stream>>>(hg1, grk, br, R, 512, 1536, 512);
  gru_gate<<<1024, 256, 0, stream>>>(X + 786432, R, 1536, hg1, hg2);
  // GRU t=2 -> new_state straight into d_out tail
  gemm_k<0><<<4 * 12, 256, 0, stream>>>(hg2, grk, br, R, 512, 1536, 512);
  gru_gate<<<1024, 256, 0, stream>>>(X + 1572864, R, 1536, hg2, h3);
  // g = [y | ctx | new_state]
  pack3<<<dim3(1024, 3), 256, 0, stream>>>(y, ctx, h3, g, 1);
  // dense stack
  gemm_k<1><<<4 * 40, 256, 0, stream>>>(g, w1, b1, dd1, 512, H_DIM, 1536);
  gemm_k<1><<<4 * 40, 256, 0, stream>>>(dd1, w2, b2, dd2, 512, H_DIM, H_DIM);
  gemm_k<0><<<4 * 250, 256, 0, stream>>>(dd2, w3, b3, g_out, 512, V_DIM, H_DIM);
  softmax_rows<<<512, 256, 0, stream>>>(g_out);
}